// Round 3
// baseline (967.863 us; speedup 1.0000x reference)
//
#include <hip/hip_runtime.h>
#include <cstdint>

#define NNODES 50000
#define NEDGES 800000
#define NEG 0.2f

__device__ __forceinline__ float leaky(float v) { return v > 0.f ? v : NEG * v; }

// K1: h = x @ W   [50000,128] x [128,128] fp32
__global__ __launch_bounds__(256) void gemm_k(const float* __restrict__ x,
                                              const float* __restrict__ W,
                                              float* __restrict__ h) {
    __shared__ float xs[32][128];
    const int tid = threadIdx.x;
    const int rbase = blockIdx.x * 32;
    #pragma unroll
    for (int i = 0; i < 16; ++i) {
        int idx = tid + i * 256;
        int r = idx >> 7, k = idx & 127;
        int gr = rbase + r;
        xs[r][k] = (gr < NNODES) ? x[(size_t)gr * 128 + k] : 0.f;
    }
    __syncthreads();
    const int cp = tid & 63;   // column pair: cols 2cp, 2cp+1
    const int rg = tid >> 6;   // row group: rows rg*8 .. rg*8+7
    float acc0[8], acc1[8];
    #pragma unroll
    for (int r = 0; r < 8; ++r) { acc0[r] = 0.f; acc1[r] = 0.f; }
    const float2* W2 = (const float2*)W;
    for (int k = 0; k < 128; k += 4) {
        float2 w0 = W2[(k + 0) * 64 + cp];
        float2 w1 = W2[(k + 1) * 64 + cp];
        float2 w2 = W2[(k + 2) * 64 + cp];
        float2 w3 = W2[(k + 3) * 64 + cp];
        #pragma unroll
        for (int r = 0; r < 8; ++r) {
            float4 xv = *(const float4*)&xs[rg * 8 + r][k];  // wave-uniform -> LDS broadcast
            acc0[r] += xv.x * w0.x; acc1[r] += xv.x * w0.y;
            acc0[r] += xv.y * w1.x; acc1[r] += xv.y * w1.y;
            acc0[r] += xv.z * w2.x; acc1[r] += xv.z * w2.y;
            acc0[r] += xv.w * w3.x; acc1[r] += xv.w * w3.y;
        }
    }
    float2* h2 = (float2*)h;
    #pragma unroll
    for (int r = 0; r < 8; ++r) {
        int row = rbase + rg * 8 + r;
        if (row < NNODES) h2[(size_t)row * 64 + cp] = make_float2(acc0[r], acc1[r]);
    }
}

// K2: per-node attention logits a_src[n,h], a_dst[n,h]. One wave per node.
__global__ __launch_bounds__(256) void logits_k(const float* __restrict__ h,
                                                const float* __restrict__ att_src,
                                                const float* __restrict__ att_dst,
                                                float* __restrict__ a_src,
                                                float* __restrict__ a_dst) {
    const int wid = threadIdx.x >> 6, lane = threadIdx.x & 63;
    const int n = blockIdx.x * 4 + wid;
    if (n >= NNODES) return;
    float2 hv = ((const float2*)(h + (size_t)n * 128))[lane];
    const int head = lane >> 4;           // 16 lanes per head (2 chans each)
    const int c0 = (2 * lane) & 31;
    float ps = hv.x * att_src[head * 32 + c0] + hv.y * att_src[head * 32 + c0 + 1];
    float pd = hv.x * att_dst[head * 32 + c0] + hv.y * att_dst[head * 32 + c0 + 1];
    #pragma unroll
    for (int m = 8; m >= 1; m >>= 1) {
        ps += __shfl_xor(ps, m, 16);
        pd += __shfl_xor(pd, m, 16);
    }
    if ((lane & 15) == 0) {
        a_src[n * 4 + head] = ps;
        a_dst[n * 4 + head] = pd;
    }
}

// K3: unnormalized self-loop numerator: out = exp_self * h ; denom = exp_self
__global__ __launch_bounds__(128) void init_k(const float* __restrict__ h,
                                              const float* __restrict__ a_src,
                                              const float* __restrict__ a_dst,
                                              float* __restrict__ out,
                                              float* __restrict__ denom) {
    const int n = blockIdx.x;
    const int c = threadIdx.x;
    const int head = c >> 5;
    float es = __expf(leaky(a_src[n * 4 + head] + a_dst[n * 4 + head]));
    out[(size_t)n * 128 + c] = es * h[(size_t)n * 128 + c];
    if (c < 4) {
        float e2 = __expf(leaky(a_src[n * 4 + c] + a_dst[n * 4 + c]));
        denom[n * 4 + c] = e2;
    }
}

// K4: per-edge exp(leaky(logit)) for all 4 heads; accumulate denom[dst].
__global__ __launch_bounds__(256) void edgew_k(const int* __restrict__ ei,
                                               const float* __restrict__ a_src,
                                               const float* __restrict__ a_dst,
                                               float* __restrict__ denom) {
    const int e = blockIdx.x * 256 + threadIdx.x;
    if (e >= NEDGES) return;
    const int s = ei[e];
    const int d = ei[NEDGES + e];
    float4 as = ((const float4*)a_src)[s];
    float4 ad = ((const float4*)a_dst)[d];
    float4 w;
    w.x = __expf(leaky(as.x + ad.x));
    w.y = __expf(leaky(as.y + ad.y));
    w.z = __expf(leaky(as.z + ad.z));
    w.w = __expf(leaky(as.w + ad.w));
    float* dp = denom + (size_t)d * 4;
    unsafeAtomicAdd(dp + 0, w.x);
    unsafeAtomicAdd(dp + 1, w.y);
    unsafeAtomicAdd(dp + 2, w.z);
    unsafeAtomicAdd(dp + 3, w.w);
}

// K5: unnormalized scatter: out[dst] += w * h[src]. One wave per edge, 2 chans/lane.
__global__ __launch_bounds__(256) void scatter_k(const int* __restrict__ ei,
                                                 const float* __restrict__ h,
                                                 const float* __restrict__ a_src,
                                                 const float* __restrict__ a_dst,
                                                 float* __restrict__ out) {
    const int wid = threadIdx.x >> 6, lane = threadIdx.x & 63;
    const int e = blockIdx.x * 4 + wid;
    if (e >= NEDGES) return;
    const int s = ei[e];
    const int d = ei[NEDGES + e];
    const int head = lane >> 4;
    float w = __expf(leaky(a_src[s * 4 + head] + a_dst[d * 4 + head]));
    float2 hv = ((const float2*)(h + (size_t)s * 128))[lane];
    float* op = out + (size_t)d * 128 + 2 * lane;
    unsafeAtomicAdd(op + 0, w * hv.x);
    unsafeAtomicAdd(op + 1, w * hv.y);
}

// K6: normalize + bias: out = out / denom[head] + bias. 2 nodes per block.
__global__ __launch_bounds__(256) void final_k(const float* __restrict__ denom,
                                               const float* __restrict__ bias,
                                               float* __restrict__ out) {
    const int n = blockIdx.x * 2 + (threadIdx.x >> 7);
    const int c = threadIdx.x & 127;
    const int head = c >> 5;
    float inv = __frcp_rn(denom[n * 4 + head]);
    size_t idx = (size_t)n * 128 + c;
    out[idx] = out[idx] * inv + bias[c];
}

extern "C" void kernel_launch(void* const* d_in, const int* in_sizes, int n_in,
                              void* d_out, int out_size, void* d_ws, size_t ws_size,
                              hipStream_t stream) {
    const float* x     = (const float*)d_in[0];
    const int*   ei    = (const int*)d_in[1];     // int64 in reference -> delivered as int32
    const float* W     = (const float*)d_in[2];
    const float* att_s = (const float*)d_in[3];
    const float* att_d = (const float*)d_in[4];
    const float* bias  = (const float*)d_in[5];
    float*       out   = (float*)d_out;
    char*        ws    = (char*)d_ws;

    // ws layout (bytes): h 25.6MB | a_src 0.8MB | a_dst 0.8MB | denom 0.8MB  (28MB total)
    float* h     = (float*)(ws);
    float* a_src = (float*)(ws + 25600000);
    float* a_dst = (float*)(ws + 26400000);
    float* denom = (float*)(ws + 27200000);

    gemm_k   <<<1563,   256, 0, stream>>>(x, W, h);
    logits_k <<<12500,  256, 0, stream>>>(h, att_s, att_d, a_src, a_dst);
    init_k   <<<50000,  128, 0, stream>>>(h, a_src, a_dst, out, denom);
    edgew_k  <<<3125,   256, 0, stream>>>(ei, a_src, a_dst, denom);
    scatter_k<<<200000, 256, 0, stream>>>(ei, h, a_src, a_dst, out);
    final_k  <<<25000,  256, 0, stream>>>(denom, bias, out);
}

// Round 4
// 392.937 us; speedup vs baseline: 2.4632x; 2.4632x over previous
//
#include <hip/hip_runtime.h>
#include <cstdint>

#define NNODES 50000
#define NEDGES 800000
#define NEG 0.2f

__device__ __forceinline__ float leaky(float v) { return v > 0.f ? v : NEG * v; }

// K1: h = x @ W   [50000,128] x [128,128] fp32
__global__ __launch_bounds__(256) void gemm_k(const float* __restrict__ x,
                                              const float* __restrict__ W,
                                              float* __restrict__ h) {
    __shared__ float xs[32][128];
    const int tid = threadIdx.x;
    const int rbase = blockIdx.x * 32;
    #pragma unroll
    for (int i = 0; i < 16; ++i) {
        int idx = tid + i * 256;
        int r = idx >> 7, k = idx & 127;
        int gr = rbase + r;
        xs[r][k] = (gr < NNODES) ? x[(size_t)gr * 128 + k] : 0.f;
    }
    __syncthreads();
    const int cp = tid & 63;
    const int rg = tid >> 6;
    float acc0[8], acc1[8];
    #pragma unroll
    for (int r = 0; r < 8; ++r) { acc0[r] = 0.f; acc1[r] = 0.f; }
    const float2* W2 = (const float2*)W;
    for (int k = 0; k < 128; k += 4) {
        float2 w0 = W2[(k + 0) * 64 + cp];
        float2 w1 = W2[(k + 1) * 64 + cp];
        float2 w2 = W2[(k + 2) * 64 + cp];
        float2 w3 = W2[(k + 3) * 64 + cp];
        #pragma unroll
        for (int r = 0; r < 8; ++r) {
            float4 xv = *(const float4*)&xs[rg * 8 + r][k];
            acc0[r] += xv.x * w0.x; acc1[r] += xv.x * w0.y;
            acc0[r] += xv.y * w1.x; acc1[r] += xv.y * w1.y;
            acc0[r] += xv.z * w2.x; acc1[r] += xv.z * w2.y;
            acc0[r] += xv.w * w3.x; acc1[r] += xv.w * w3.y;
        }
    }
    float2* h2 = (float2*)h;
    #pragma unroll
    for (int r = 0; r < 8; ++r) {
        int row = rbase + rg * 8 + r;
        if (row < NNODES) h2[(size_t)row * 64 + cp] = make_float2(acc0[r], acc1[r]);
    }
}

// K2: per-node attention logits a_src[n,h], a_dst[n,h]. One wave per node.
__global__ __launch_bounds__(256) void logits_k(const float* __restrict__ h,
                                                const float* __restrict__ att_src,
                                                const float* __restrict__ att_dst,
                                                float* __restrict__ a_src,
                                                float* __restrict__ a_dst) {
    const int wid = threadIdx.x >> 6, lane = threadIdx.x & 63;
    const int n = blockIdx.x * 4 + wid;
    if (n >= NNODES) return;
    float2 hv = ((const float2*)(h + (size_t)n * 128))[lane];
    const int head = lane >> 4;
    const int c0 = (2 * lane) & 31;
    float ps = hv.x * att_src[head * 32 + c0] + hv.y * att_src[head * 32 + c0 + 1];
    float pd = hv.x * att_dst[head * 32 + c0] + hv.y * att_dst[head * 32 + c0 + 1];
    #pragma unroll
    for (int m = 8; m >= 1; m >>= 1) {
        ps += __shfl_xor(ps, m, 16);
        pd += __shfl_xor(pd, m, 16);
    }
    if ((lane & 15) == 0) {
        a_src[n * 4 + head] = ps;
        a_dst[n * 4 + head] = pd;
    }
}

// K3: histogram of dst degrees (deg pre-zeroed by hipMemsetAsync)
__global__ __launch_bounds__(256) void hist_k(const int* __restrict__ ei,
                                              int* __restrict__ deg) {
    const int e = blockIdx.x * 256 + threadIdx.x;
    if (e >= NEDGES) return;
    atomicAdd(&deg[ei[NEDGES + e]], 1);
}

// K4: single-block exclusive scan of deg -> off, cur. 1024 threads, ~49 nodes each.
__global__ __launch_bounds__(1024) void scan_k(const int* __restrict__ deg,
                                               int* __restrict__ off,
                                               int* __restrict__ cur) {
    __shared__ int wsum[16];
    const int t = threadIdx.x;
    const int CH = 49;  // ceil(50000/1024)
    int beg = t * CH, end = beg + CH;
    if (beg > NNODES) beg = NNODES;
    if (end > NNODES) end = NNODES;
    int local = 0;
    for (int i = beg; i < end; ++i) local += deg[i];
    const int lane = t & 63, wv = t >> 6;
    int v = local;
    #pragma unroll
    for (int m = 1; m < 64; m <<= 1) {
        int u = __shfl_up(v, m);
        if (lane >= m) v += u;
    }
    if (lane == 63) wsum[wv] = v;
    __syncthreads();
    if (t == 0) {
        int run = 0;
        #pragma unroll
        for (int i = 0; i < 16; ++i) { int x = wsum[i]; wsum[i] = run; run += x; }
    }
    __syncthreads();
    int run = (v - local) + wsum[wv];   // exclusive prefix of this thread's chunk
    for (int i = beg; i < end; ++i) {
        off[i] = run; cur[i] = run; run += deg[i];
    }
    if (t == 0) off[NNODES] = NEDGES;
}

// K5: counting-sort fill: csr[cur[dst]++] = src
__global__ __launch_bounds__(256) void fill_k(const int* __restrict__ ei,
                                              int* __restrict__ cur,
                                              int* __restrict__ csr) {
    const int e = blockIdx.x * 256 + threadIdx.x;
    if (e >= NEDGES) return;
    const int s = ei[e];
    const int d = ei[NEDGES + e];
    int pos = atomicAdd(&cur[d], 1);
    csr[pos] = s;
}

// K6: gather per dst node: out[n] = (w_self*h[n] + sum_j w_j*h[s_j]) / denom + bias
// One wave per node; lane covers channels 2*lane, 2*lane+1; head = lane>>4.
// Chunks of 16 edges: lane computes weight for (edge=lane&15, head=lane>>4).
__global__ __launch_bounds__(256) void gather_k(const int* __restrict__ off,
                                                const int* __restrict__ csr,
                                                const float* __restrict__ h,
                                                const float* __restrict__ a_src,
                                                const float* __restrict__ a_dst,
                                                const float* __restrict__ bias,
                                                float* __restrict__ out) {
    const int wid = threadIdx.x >> 6, lane = threadIdx.x & 63;
    const int n = blockIdx.x * 4 + wid;
    if (n >= NNODES) return;
    const int head = lane >> 4;
    const int sub = lane & 15;

    const float a_d = a_dst[n * 4 + head];
    const float w_self = __expf(leaky(a_src[n * 4 + head] + a_d));
    float2 hn = ((const float2*)(h + (size_t)n * 128))[lane];
    float accx = w_self * hn.x, accy = w_self * hn.y;
    float denom = w_self;

    const int beg = off[n], end = off[n + 1];
    for (int base = beg; base < end; base += 16) {
        int m = end - base; if (m > 16) m = 16;
        int s = 0;
        float w = 0.f;
        if (sub < m) {
            s = csr[base + sub];
            w = __expf(leaky(a_src[s * 4 + head] + a_d));
        }
        if (m == 16) {
            #pragma unroll
            for (int j = 0; j < 16; ++j) {
                int   sj = __shfl(s, j);
                float wj = __shfl(w, (head << 4) | j);
                float2 hv = ((const float2*)(h + (size_t)sj * 128))[lane];
                denom += wj;
                accx += wj * hv.x; accy += wj * hv.y;
            }
        } else {
            for (int j = 0; j < m; ++j) {
                int   sj = __shfl(s, j);
                float wj = __shfl(w, (head << 4) | j);
                float2 hv = ((const float2*)(h + (size_t)sj * 128))[lane];
                denom += wj;
                accx += wj * hv.x; accy += wj * hv.y;
            }
        }
    }
    const float inv = __frcp_rn(denom);
    float2 bv = ((const float2*)bias)[lane];
    ((float2*)(out + (size_t)n * 128))[lane] =
        make_float2(accx * inv + bv.x, accy * inv + bv.y);
}

extern "C" void kernel_launch(void* const* d_in, const int* in_sizes, int n_in,
                              void* d_out, int out_size, void* d_ws, size_t ws_size,
                              hipStream_t stream) {
    const float* x     = (const float*)d_in[0];
    const int*   ei    = (const int*)d_in[1];   // int64 ref -> delivered int32
    const float* W     = (const float*)d_in[2];
    const float* att_s = (const float*)d_in[3];
    const float* att_d = (const float*)d_in[4];
    const float* bias  = (const float*)d_in[5];
    float*       out   = (float*)d_out;
    char*        ws    = (char*)d_ws;

    // ws layout (bytes):
    // h 25.6MB | a_src 0.8MB | a_dst 0.8MB | deg 200KB | off 200KB(+pad) | cur 200KB | csr 3.2MB
    float* h     = (float*)(ws);
    float* a_src = (float*)(ws + 25600000);
    float* a_dst = (float*)(ws + 26400000);
    int*   deg   = (int*)  (ws + 27200000);
    int*   off   = (int*)  (ws + 27400000);
    int*   cur   = (int*)  (ws + 27600064);
    int*   csr   = (int*)  (ws + 27800064);

    hipMemsetAsync(deg, 0, NNODES * sizeof(int), stream);
    gemm_k   <<<1563,  256,  0, stream>>>(x, W, h);
    logits_k <<<12500, 256,  0, stream>>>(h, att_s, att_d, a_src, a_dst);
    hist_k   <<<3125,  256,  0, stream>>>(ei, deg);
    scan_k   <<<1,     1024, 0, stream>>>(deg, off, cur);
    fill_k   <<<3125,  256,  0, stream>>>(ei, cur, csr);
    gather_k <<<12500, 256,  0, stream>>>(off, csr, h, a_src, a_dst, bias, out);
}

// Round 5
// 286.660 us; speedup vs baseline: 3.3763x; 1.3707x over previous
//
#include <hip/hip_runtime.h>
#include <cstdint>

#define NNODES 50000
#define NEDGES 800000
#define NEG 0.2f
#define NB 196          // ceil(50000/256) scan blocks

__device__ __forceinline__ float leaky(float v) { return v > 0.f ? v : NEG * v; }

// K1: h = x @ W   [50000,128] x [128,128] fp32
__global__ __launch_bounds__(256) void gemm_k(const float* __restrict__ x,
                                              const float* __restrict__ W,
                                              float* __restrict__ h) {
    __shared__ float xs[32][128];
    const int tid = threadIdx.x;
    const int rbase = blockIdx.x * 32;
    #pragma unroll
    for (int i = 0; i < 16; ++i) {
        int idx = tid + i * 256;
        int r = idx >> 7, k = idx & 127;
        int gr = rbase + r;
        xs[r][k] = (gr < NNODES) ? x[(size_t)gr * 128 + k] : 0.f;
    }
    __syncthreads();
    const int cp = tid & 63;
    const int rg = tid >> 6;
    float acc0[8], acc1[8];
    #pragma unroll
    for (int r = 0; r < 8; ++r) { acc0[r] = 0.f; acc1[r] = 0.f; }
    const float2* W2 = (const float2*)W;
    for (int k = 0; k < 128; k += 4) {
        float2 w0 = W2[(k + 0) * 64 + cp];
        float2 w1 = W2[(k + 1) * 64 + cp];
        float2 w2 = W2[(k + 2) * 64 + cp];
        float2 w3 = W2[(k + 3) * 64 + cp];
        #pragma unroll
        for (int r = 0; r < 8; ++r) {
            float4 xv = *(const float4*)&xs[rg * 8 + r][k];
            acc0[r] += xv.x * w0.x; acc1[r] += xv.x * w0.y;
            acc0[r] += xv.y * w1.x; acc1[r] += xv.y * w1.y;
            acc0[r] += xv.z * w2.x; acc1[r] += xv.z * w2.y;
            acc0[r] += xv.w * w3.x; acc1[r] += xv.w * w3.y;
        }
    }
    float2* h2 = (float2*)h;
    #pragma unroll
    for (int r = 0; r < 8; ++r) {
        int row = rbase + rg * 8 + r;
        if (row < NNODES) h2[(size_t)row * 64 + cp] = make_float2(acc0[r], acc1[r]);
    }
}

// K2: per-node attention logits a_src[n,h], a_dst[n,h]. One wave per node.
__global__ __launch_bounds__(256) void logits_k(const float* __restrict__ h,
                                                const float* __restrict__ att_src,
                                                const float* __restrict__ att_dst,
                                                float* __restrict__ a_src,
                                                float* __restrict__ a_dst) {
    const int wid = threadIdx.x >> 6, lane = threadIdx.x & 63;
    const int n = blockIdx.x * 4 + wid;
    if (n >= NNODES) return;
    float2 hv = ((const float2*)(h + (size_t)n * 128))[lane];
    const int head = lane >> 4;
    const int c0 = (2 * lane) & 31;
    float ps = hv.x * att_src[head * 32 + c0] + hv.y * att_src[head * 32 + c0 + 1];
    float pd = hv.x * att_dst[head * 32 + c0] + hv.y * att_dst[head * 32 + c0 + 1];
    #pragma unroll
    for (int m = 8; m >= 1; m >>= 1) {
        ps += __shfl_xor(ps, m, 16);
        pd += __shfl_xor(pd, m, 16);
    }
    if ((lane & 15) == 0) {
        a_src[n * 4 + head] = ps;
        a_dst[n * 4 + head] = pd;
    }
}

// K3: histogram of dst degrees (deg pre-zeroed by hipMemsetAsync)
__global__ __launch_bounds__(256) void hist_k(const int* __restrict__ ei,
                                              int* __restrict__ deg) {
    const int e = blockIdx.x * 256 + threadIdx.x;
    if (e >= NEDGES) return;
    atomicAdd(&deg[ei[NEDGES + e]], 1);
}

// ---- multi-block exclusive scan of deg[50000] -> off/cur ----
__device__ __forceinline__ int block_excl_scan(int v, int t, int* total) {
    // 256-thread block exclusive scan; returns exclusive prefix; *total on t==255 path via LDS
    __shared__ int wsum[4];
    const int lane = t & 63, wv = t >> 6;
    int x = v;
    #pragma unroll
    for (int m = 1; m < 64; m <<= 1) {
        int u = __shfl_up(x, m);
        if (lane >= m) x += u;
    }
    if (lane == 63) wsum[wv] = x;
    __syncthreads();
    if (t == 0) {
        int run = 0;
        #pragma unroll
        for (int i = 0; i < 4; ++i) { int tmp = wsum[i]; wsum[i] = run; run += tmp; }
    }
    __syncthreads();
    int excl = x - v + wsum[wv];
    if (total) *total = wsum[3];  // after t==0 rewrite, wsum[3] = sum of waves 0..2; need add wave3 total
    return excl;
}

// A: per-block scan; off[i] = in-block exclusive prefix; bsum[b] = block total
__global__ __launch_bounds__(256) void scanA_k(const int* __restrict__ deg,
                                               int* __restrict__ off,
                                               int* __restrict__ bsum) {
    const int b = blockIdx.x, t = threadIdx.x;
    const int i = b * 256 + t;
    int v = (i < NNODES) ? deg[i] : 0;
    int excl = block_excl_scan(v, t, nullptr);
    if (i < NNODES) off[i] = excl;
    if (t == 255) bsum[b] = excl + v;
}

// B: scan the 196 block totals
__global__ __launch_bounds__(256) void scanB_k(int* __restrict__ bsum,
                                               int* __restrict__ bofs) {
    const int t = threadIdx.x;
    int v = (t < NB) ? bsum[t] : 0;
    int excl = block_excl_scan(v, t, nullptr);
    if (t < NB) bofs[t] = excl;
}

// C: add block offset, produce final off & cur
__global__ __launch_bounds__(256) void scanC_k(int* __restrict__ off,
                                               const int* __restrict__ bofs,
                                               int* __restrict__ cur) {
    const int b = blockIdx.x, t = threadIdx.x;
    const int i = b * 256 + t;
    if (i < NNODES) {
        int o = off[i] + bofs[b];
        off[i] = o;
        cur[i] = o;
    }
    if (b == 0 && t == 0) off[NNODES] = NEDGES;
}

// K5: counting-sort fill: csr[cur[dst]++] = src
__global__ __launch_bounds__(256) void fill_k(const int* __restrict__ ei,
                                              int* __restrict__ cur,
                                              int* __restrict__ csr) {
    const int e = blockIdx.x * 256 + threadIdx.x;
    if (e >= NEDGES) return;
    const int s = ei[e];
    const int d = ei[NEDGES + e];
    int pos = atomicAdd(&cur[d], 1);
    csr[pos] = s;
}

// K6: gather per dst node: out[n] = (w_self*h[n] + sum_j w_j*h[s_j]) / denom + bias
__global__ __launch_bounds__(256) void gather_k(const int* __restrict__ off,
                                                const int* __restrict__ csr,
                                                const float* __restrict__ h,
                                                const float* __restrict__ a_src,
                                                const float* __restrict__ a_dst,
                                                const float* __restrict__ bias,
                                                float* __restrict__ out) {
    const int wid = threadIdx.x >> 6, lane = threadIdx.x & 63;
    const int n = blockIdx.x * 4 + wid;
    if (n >= NNODES) return;
    const int head = lane >> 4;
    const int sub = lane & 15;

    const float a_d = a_dst[n * 4 + head];
    const float w_self = __expf(leaky(a_src[n * 4 + head] + a_d));
    float2 hn = ((const float2*)(h + (size_t)n * 128))[lane];
    float accx = w_self * hn.x, accy = w_self * hn.y;
    float denom = w_self;

    const int beg = off[n], end = off[n + 1];
    for (int base = beg; base < end; base += 16) {
        int m = end - base; if (m > 16) m = 16;
        int s = 0;
        float w = 0.f;
        if (sub < m) {
            s = csr[base + sub];
            w = __expf(leaky(a_src[s * 4 + head] + a_d));
        }
        if (m == 16) {
            #pragma unroll
            for (int j = 0; j < 16; ++j) {
                int   sj = __shfl(s, j);
                float wj = __shfl(w, (head << 4) | j);
                float2 hv = ((const float2*)(h + (size_t)sj * 128))[lane];
                denom += wj;
                accx += wj * hv.x; accy += wj * hv.y;
            }
        } else {
            for (int j = 0; j < m; ++j) {
                int   sj = __shfl(s, j);
                float wj = __shfl(w, (head << 4) | j);
                float2 hv = ((const float2*)(h + (size_t)sj * 128))[lane];
                denom += wj;
                accx += wj * hv.x; accy += wj * hv.y;
            }
        }
    }
    const float inv = __frcp_rn(denom);
    float2 bv = ((const float2*)bias)[lane];
    ((float2*)(out + (size_t)n * 128))[lane] =
        make_float2(accx * inv + bv.x, accy * inv + bv.y);
}

extern "C" void kernel_launch(void* const* d_in, const int* in_sizes, int n_in,
                              void* d_out, int out_size, void* d_ws, size_t ws_size,
                              hipStream_t stream) {
    const float* x     = (const float*)d_in[0];
    const int*   ei    = (const int*)d_in[1];   // int64 ref -> delivered int32
    const float* W     = (const float*)d_in[2];
    const float* att_s = (const float*)d_in[3];
    const float* att_d = (const float*)d_in[4];
    const float* bias  = (const float*)d_in[5];
    float*       out   = (float*)d_out;
    char*        ws    = (char*)d_ws;

    // ws layout (bytes):
    // h 25.6MB | a_src 0.8MB | a_dst 0.8MB | deg 200KB | off 200KB+4 | cur 200KB | csr 3.2MB | bsum | bofs
    float* h     = (float*)(ws);
    float* a_src = (float*)(ws + 25600000);
    float* a_dst = (float*)(ws + 26400000);
    int*   deg   = (int*)  (ws + 27200000);
    int*   off   = (int*)  (ws + 27400000);
    int*   cur   = (int*)  (ws + 27600064);
    int*   csr   = (int*)  (ws + 27800064);
    int*   bsum  = (int*)  (ws + 31000064);
    int*   bofs  = (int*)  (ws + 31001088);

    hipMemsetAsync(deg, 0, NNODES * sizeof(int), stream);
    gemm_k   <<<1563,  256, 0, stream>>>(x, W, h);
    logits_k <<<12500, 256, 0, stream>>>(h, att_s, att_d, a_src, a_dst);
    hist_k   <<<3125,  256, 0, stream>>>(ei, deg);
    scanA_k  <<<NB,    256, 0, stream>>>(deg, off, bsum);
    scanB_k  <<<1,     256, 0, stream>>>(bsum, bofs);
    scanC_k  <<<NB,    256, 0, stream>>>(off, bofs, cur);
    fill_k   <<<3125,  256, 0, stream>>>(ei, cur, csr);
    gather_k <<<12500, 256, 0, stream>>>(off, csr, h, a_src, a_dst, bias, out);
}

// Round 6
// 260.046 us; speedup vs baseline: 3.7219x; 1.1023x over previous
//
#include <hip/hip_runtime.h>
#include <cstdint>

#define NNODES 50000
#define NEDGES 800000
#define NEG 0.2f
#define NB 196          // ceil(50000/256) scan blocks

__device__ __forceinline__ float leaky(float v) { return v > 0.f ? v : NEG * v; }

__device__ __forceinline__ unsigned short f2bf(float f) {   // round-to-nearest-even
    unsigned int u = __float_as_uint(f);
    u += 0x7fff + ((u >> 16) & 1);
    return (unsigned short)(u >> 16);
}

// K1: h = x @ W  [50000,128]x[128,128] fp32 compute; h stored bf16; logits fused.
// Block 256 threads, tile 32 rows. Wave rg owns rows rg*8..rg*8+7 fully:
// lane cp holds cols 2cp,2cp+1 -> head = cp>>4 (16 lanes per head).
__global__ __launch_bounds__(256) void gemm_k(const float* __restrict__ x,
                                              const float* __restrict__ W,
                                              unsigned short* __restrict__ hb,
                                              const float* __restrict__ att_src,
                                              const float* __restrict__ att_dst,
                                              float* __restrict__ a_src,
                                              float* __restrict__ a_dst) {
    __shared__ float xs[32][128];
    const int tid = threadIdx.x;
    const int rbase = blockIdx.x * 32;
    #pragma unroll
    for (int i = 0; i < 16; ++i) {
        int idx = tid + i * 256;
        int r = idx >> 7, k = idx & 127;
        int gr = rbase + r;
        xs[r][k] = (gr < NNODES) ? x[(size_t)gr * 128 + k] : 0.f;
    }
    __syncthreads();
    const int cp = tid & 63;
    const int rg = tid >> 6;
    float acc0[8], acc1[8];
    #pragma unroll
    for (int r = 0; r < 8; ++r) { acc0[r] = 0.f; acc1[r] = 0.f; }
    const float2* W2 = (const float2*)W;
    for (int k = 0; k < 128; k += 4) {
        float2 w0 = W2[(k + 0) * 64 + cp];
        float2 w1 = W2[(k + 1) * 64 + cp];
        float2 w2 = W2[(k + 2) * 64 + cp];
        float2 w3 = W2[(k + 3) * 64 + cp];
        #pragma unroll
        for (int r = 0; r < 8; ++r) {
            float4 xv = *(const float4*)&xs[rg * 8 + r][k];  // wave-uniform -> LDS broadcast
            acc0[r] += xv.x * w0.x; acc1[r] += xv.x * w0.y;
            acc0[r] += xv.y * w1.x; acc1[r] += xv.y * w1.y;
            acc0[r] += xv.z * w2.x; acc1[r] += xv.z * w2.y;
            acc0[r] += xv.w * w3.x; acc1[r] += xv.w * w3.y;
        }
    }
    // epilogue: bf16 store + fused per-(row,head) logits
    float2 as_v = ((const float2*)att_src)[cp];
    float2 ad_v = ((const float2*)att_dst)[cp];
    #pragma unroll
    for (int r = 0; r < 8; ++r) {
        int row = rbase + rg * 8 + r;
        ushort2 hs;
        hs.x = f2bf(acc0[r]); hs.y = f2bf(acc1[r]);
        if (row < NNODES) ((ushort2*)(hb + (size_t)row * 128))[cp] = hs;
        float ps = acc0[r] * as_v.x + acc1[r] * as_v.y;
        float pd = acc0[r] * ad_v.x + acc1[r] * ad_v.y;
        #pragma unroll
        for (int m = 8; m >= 1; m >>= 1) {
            ps += __shfl_xor(ps, m, 16);
            pd += __shfl_xor(pd, m, 16);
        }
        if (row < NNODES && (cp & 15) == 0) {
            a_src[row * 4 + (cp >> 4)] = ps;
            a_dst[row * 4 + (cp >> 4)] = pd;
        }
    }
}

// K3: histogram of dst degrees (deg pre-zeroed by hipMemsetAsync)
__global__ __launch_bounds__(256) void hist_k(const int* __restrict__ ei,
                                              int* __restrict__ deg) {
    const int e = blockIdx.x * 256 + threadIdx.x;
    if (e >= NEDGES) return;
    atomicAdd(&deg[ei[NEDGES + e]], 1);
}

// ---- multi-block exclusive scan of deg[50000] -> off/cur ----
__device__ __forceinline__ int block_excl_scan(int v, int t) {
    __shared__ int wsum[4];
    const int lane = t & 63, wv = t >> 6;
    int x = v;
    #pragma unroll
    for (int m = 1; m < 64; m <<= 1) {
        int u = __shfl_up(x, m);
        if (lane >= m) x += u;
    }
    if (lane == 63) wsum[wv] = x;
    __syncthreads();
    if (t == 0) {
        int run = 0;
        #pragma unroll
        for (int i = 0; i < 4; ++i) { int tmp = wsum[i]; wsum[i] = run; run += tmp; }
    }
    __syncthreads();
    return x - v + wsum[wv];
}

__global__ __launch_bounds__(256) void scanA_k(const int* __restrict__ deg,
                                               int* __restrict__ off,
                                               int* __restrict__ bsum) {
    const int b = blockIdx.x, t = threadIdx.x;
    const int i = b * 256 + t;
    int v = (i < NNODES) ? deg[i] : 0;
    int excl = block_excl_scan(v, t);
    if (i < NNODES) off[i] = excl;
    if (t == 255) bsum[b] = excl + v;
}

__global__ __launch_bounds__(256) void scanB_k(int* __restrict__ bsum,
                                               int* __restrict__ bofs) {
    const int t = threadIdx.x;
    int v = (t < NB) ? bsum[t] : 0;
    int excl = block_excl_scan(v, t);
    if (t < NB) bofs[t] = excl;
}

__global__ __launch_bounds__(256) void scanC_k(int* __restrict__ off,
                                               const int* __restrict__ bofs,
                                               int* __restrict__ cur) {
    const int b = blockIdx.x, t = threadIdx.x;
    const int i = b * 256 + t;
    if (i < NNODES) {
        int o = off[i] + bofs[b];
        off[i] = o;
        cur[i] = o;
    }
    if (b == 0 && t == 0) off[NNODES] = NEDGES;
}

// K5: counting-sort fill: csr[cur[dst]++] = src
__global__ __launch_bounds__(256) void fill_k(const int* __restrict__ ei,
                                              int* __restrict__ cur,
                                              int* __restrict__ csr) {
    const int e = blockIdx.x * 256 + threadIdx.x;
    if (e >= NEDGES) return;
    const int s = ei[e];
    const int d = ei[NEDGES + e];
    int pos = atomicAdd(&cur[d], 1);
    csr[pos] = s;
}

// K6: gather per dst node from bf16 h: out[n] = (w_self*h[n] + sum w_j*h[s_j])/denom + bias
__global__ __launch_bounds__(256) void gather_k(const int* __restrict__ off,
                                                const int* __restrict__ csr,
                                                const unsigned short* __restrict__ hb,
                                                const float* __restrict__ a_src,
                                                const float* __restrict__ a_dst,
                                                const float* __restrict__ bias,
                                                float* __restrict__ out) {
    const int wid = threadIdx.x >> 6, lane = threadIdx.x & 63;
    const int n = blockIdx.x * 4 + wid;
    if (n >= NNODES) return;
    const int head = lane >> 4;
    const int sub = lane & 15;

    const float a_d = a_dst[n * 4 + head];
    const float w_self = __expf(leaky(a_src[n * 4 + head] + a_d));
    unsigned int hv0 = ((const unsigned int*)(hb + (size_t)n * 128))[lane];
    float hnx = __uint_as_float(hv0 << 16);
    float hny = __uint_as_float(hv0 & 0xffff0000u);
    float accx = w_self * hnx, accy = w_self * hny;
    float denom = w_self;

    const int beg = off[n], end = off[n + 1];
    for (int base = beg; base < end; base += 16) {
        int m = end - base; if (m > 16) m = 16;
        int s = 0;
        float w = 0.f;
        if (sub < m) {
            s = csr[base + sub];
            w = __expf(leaky(a_src[s * 4 + head] + a_d));
        }
        if (m == 16) {
            #pragma unroll
            for (int j = 0; j < 16; ++j) {
                int   sj = __shfl(s, j);
                float wj = __shfl(w, (head << 4) | j);
                unsigned int hv = ((const unsigned int*)(hb + (size_t)sj * 128))[lane];
                float hx = __uint_as_float(hv << 16);
                float hy = __uint_as_float(hv & 0xffff0000u);
                denom += wj;
                accx += wj * hx; accy += wj * hy;
            }
        } else {
            for (int j = 0; j < m; ++j) {
                int   sj = __shfl(s, j);
                float wj = __shfl(w, (head << 4) | j);
                unsigned int hv = ((const unsigned int*)(hb + (size_t)sj * 128))[lane];
                float hx = __uint_as_float(hv << 16);
                float hy = __uint_as_float(hv & 0xffff0000u);
                denom += wj;
                accx += wj * hx; accy += wj * hy;
            }
        }
    }
    const float inv = __frcp_rn(denom);
    float2 bv = ((const float2*)bias)[lane];
    ((float2*)(out + (size_t)n * 128))[lane] =
        make_float2(accx * inv + bv.x, accy * inv + bv.y);
}

extern "C" void kernel_launch(void* const* d_in, const int* in_sizes, int n_in,
                              void* d_out, int out_size, void* d_ws, size_t ws_size,
                              hipStream_t stream) {
    const float* x     = (const float*)d_in[0];
    const int*   ei    = (const int*)d_in[1];   // int64 ref -> delivered int32
    const float* W     = (const float*)d_in[2];
    const float* att_s = (const float*)d_in[3];
    const float* att_d = (const float*)d_in[4];
    const float* bias  = (const float*)d_in[5];
    float*       out   = (float*)d_out;
    char*        ws    = (char*)d_ws;

    // ws layout (bytes):
    // hb (bf16) 12.8MB | a_src 0.8MB | a_dst 0.8MB | deg 200KB | off 200KB+4 | cur 200KB | csr 3.2MB | bsum | bofs
    unsigned short* hb  = (unsigned short*)(ws);
    float* a_src = (float*)(ws + 12800000);
    float* a_dst = (float*)(ws + 13600000);
    int*   deg   = (int*)  (ws + 14400000);
    int*   off   = (int*)  (ws + 14600000);
    int*   cur   = (int*)  (ws + 14800064);
    int*   csr   = (int*)  (ws + 15000064);
    int*   bsum  = (int*)  (ws + 18200064);
    int*   bofs  = (int*)  (ws + 18201088);

    hipMemsetAsync(deg, 0, NNODES * sizeof(int), stream);
    gemm_k   <<<1563,  256, 0, stream>>>(x, W, hb, att_s, att_d, a_src, a_dst);
    hist_k   <<<3125,  256, 0, stream>>>(ei, deg);
    scanA_k  <<<NB,    256, 0, stream>>>(deg, off, bsum);
    scanB_k  <<<1,     256, 0, stream>>>(bsum, bofs);
    scanC_k  <<<NB,    256, 0, stream>>>(off, bofs, cur);
    fill_k   <<<3125,  256, 0, stream>>>(ei, cur, csr);
    gather_k <<<12500, 256, 0, stream>>>(off, csr, hb, a_src, a_dst, bias, out);
}